// Round 12
// baseline (890.137 us; speedup 1.0000x reference)
//
#include <hip/hip_runtime.h>
#include <hip/hip_bf16.h>

// WaveOperator: Fourier-domain 3-term recurrence + per-row inverse FFT sampling.
// A_{t+1}(p,q) = (2-4*fil(p,q)) * A_t - A_{t-1};  y[b,j,t] = Re(ifft2(A_{t+1})[u_j,v_j])
// R28 = R27 (proven 719us sim / 782.7us total) + batched vcc loads in the xor1/xor2 stages.
// R27 issued 8 asm blocks per FFT each reloading vcc (2 s_mov + 2 s_nop per block = 32 wasted
// issue slots + 8 serialization points per FFT). The masks are 2 constants per stage, so each
// stage becomes two batched blocks: vcc=kA once -> 8 a-side cndmask_dpp; vcc=kB once -> 8
// b-side. -24 issue slots/FFT (~11% of the instruction stream), routing bit-identical
// (a-sides and b-sides both read ORIGINAL G; outputs early-clobbered temps).
// History: VGPR=64 allocator-pinned (cap 84 at 6 waves/SIMD); register-neutral VALU/LDS/issue
// stream cuts are the only working lever: R23 +4%, R24 +11% (VOP3P), R25 +6% (cndmask_dpp),
// R26/27 xor4 off LDS +1.3%. Spill tripwire: FETCH_SIZE must stay ~11.46GB.

#define NOUT 512
#define NB 16
#define NPHI 256
#define NT 240
#define RPB 6             // rows per block (= waves per block)
#define NGRP 43           // row groups: 43*6 = 258 = rows 0..257 (257 gets zero phase)

#define WREG 5184         // per-wave LDS publish region (pitch 80; lane uses 2x32B parity bufs)

typedef float v2f __attribute__((ext_vector_type(2)));
typedef float v4f __attribute__((ext_vector_type(4)));
typedef unsigned int v2u __attribute__((ext_vector_type(2)));

// ---- VOP3P packed-fp32 primitives (register-neutral; modifiers do the swizzles) -----------------
__device__ __forceinline__ v2f pkadd(v2f a, v2f b) {
    v2f d; asm("v_pk_add_f32 %0, %1, %2" : "=v"(d) : "v"(a), "v"(b)); return d;
}
__device__ __forceinline__ v2f pksub(v2f a, v2f b) {
    v2f d; asm("v_pk_add_f32 %0, %1, %2 neg_lo:[0,1] neg_hi:[0,1]" : "=v"(d) : "v"(a), "v"(b)); return d;
}
// a + i*w = {a.x - w.y, a.y + w.x}
__device__ __forceinline__ v2f pkaddi(v2f a, v2f w) {
    v2f d; asm("v_pk_add_f32 %0, %1, %2 op_sel:[0,1] op_sel_hi:[1,0] neg_lo:[0,1]"
               : "=v"(d) : "v"(a), "v"(w)); return d;
}
// a - i*w = {a.x + w.y, a.y - w.x}
__device__ __forceinline__ v2f pksubi(v2f a, v2f w) {
    v2f d; asm("v_pk_add_f32 %0, %1, %2 op_sel:[0,1] op_sel_hi:[1,0] neg_hi:[0,1]"
               : "=v"(d) : "v"(a), "v"(w)); return d;
}
// s * {a.x - a.y, a.x + a.y}   (w8 twiddle)
__device__ __forceinline__ v2f pkw8(v2f a) {
    v2f d; asm("v_pk_add_f32 %0, %1, %1 op_sel:[0,1] op_sel_hi:[0,1] neg_lo:[0,1]"
               : "=v"(d) : "v"(a));
    const float s = 0.70710678118654752f;
    return v2f{s * d.x, s * d.y};
}
// {-s*(a.x + a.y), s*(a.x - a.y)}   (w8^3 twiddle)
__device__ __forceinline__ v2f pkw83(v2f a) {
    v2f d; asm("v_pk_add_f32 %0, %1, %1 op_sel:[0,1] op_sel_hi:[0,1] neg_hi:[0,1]"
               : "=v"(d) : "v"(a));
    const float s = 0.70710678118654752f;
    return v2f{-s * d.x, s * d.y};
}
// complex mul g*t: {g.x*t.x - g.y*t.y, g.x*t.y + g.y*t.x} in 2 VOP3P ops
__device__ __forceinline__ v2f cmulv(v2f g, v2f t) {
    v2f p, d;
    asm("v_pk_mul_f32 %0, %1, %2 op_sel:[0,0] op_sel_hi:[0,1]" : "=v"(p) : "v"(g), "v"(t));
    // p = {g.x*t.x, g.x*t.y}
    asm("v_pk_fma_f32 %0, %1, %2, %3 op_sel:[1,1,0] op_sel_hi:[1,0,1] neg_lo:[1,0,0]"
        : "=v"(d) : "v"(g), "v"(t), "v"(p));
    // d = {-g.y*t.y + p.x, g.y*t.x + p.y}
    return d;
}

// 8-pt DFT, positive exponent: Y[k] = sum_r y[r] * exp(+2pi i rk/8)  (packed form)
__device__ __forceinline__ void dft8p(const v2f y[8], v2f Y[8]) {
    v2f t0 = pkadd(y[0], y[4]), t4 = pksub(y[0], y[4]);
    v2f t1 = pkadd(y[1], y[5]), t5 = pkw8(pksub(y[1], y[5]));
    v2f t2 = pkadd(y[2], y[6]), d26 = pksub(y[2], y[6]);   // t6 = i*d26 folded into consumers
    v2f t3 = pkadd(y[3], y[7]), t7 = pkw83(pksub(y[3], y[7]));
    v2f u0 = pkadd(t0, t2), u2 = pksub(t0, t2);
    v2f u1 = pkadd(t1, t3), w13 = pksub(t1, t3);           // u3 = i*w13 folded
    Y[0] = pkadd(u0, u1); Y[4] = pksub(u0, u1);
    Y[2] = pkaddi(u2, w13); Y[6] = pksubi(u2, w13);
    v2f v0 = pkaddi(t4, d26), v2 = pksubi(t4, d26);        // t4 +- i*d26
    v2f v1 = pkadd(t5, t7), w57 = pksub(t5, t7);           // v3 = i*w57 folded
    Y[1] = pkadd(v0, v1); Y[5] = pksub(v0, v1);
    Y[3] = pkaddi(v2, w57); Y[7] = pksubi(v2, w57);
}

// in-place variant (reads of y[] only in the t-layer; all writes after)
__device__ __forceinline__ void dft8p_ip(v2f y[8]) {
    v2f t0 = pkadd(y[0], y[4]), t4 = pksub(y[0], y[4]);
    v2f t1 = pkadd(y[1], y[5]), t5 = pkw8(pksub(y[1], y[5]));
    v2f t2 = pkadd(y[2], y[6]), d26 = pksub(y[2], y[6]);
    v2f t3 = pkadd(y[3], y[7]), t7 = pkw83(pksub(y[3], y[7]));
    v2f u0 = pkadd(t0, t2), u2 = pksub(t0, t2);
    v2f u1 = pkadd(t1, t3), w13 = pksub(t1, t3);
    y[0] = pkadd(u0, u1); y[4] = pksub(u0, u1);
    y[2] = pkaddi(u2, w13); y[6] = pksubi(u2, w13);
    v2f v0 = pkaddi(t4, d26), v2 = pksubi(t4, d26);
    v2f v1 = pkadd(t5, t7), w57 = pksub(t5, t7);
    y[1] = pkadd(v0, v1); y[5] = pksub(v0, v1);
    y[3] = pkaddi(v2, w57); y[7] = pksubi(v2, w57);
}

// final-layer DFT producing only outputs Y2,Y3,Y4,Y5 (the sensor v>>6 range)
__device__ __forceinline__ void dft8p_mid4(const v2f y[8], v2f o[4]) {
    v2f t0 = pkadd(y[0], y[4]), t4 = pksub(y[0], y[4]);
    v2f t1 = pkadd(y[1], y[5]), t5 = pkw8(pksub(y[1], y[5]));
    v2f t2 = pkadd(y[2], y[6]), d26 = pksub(y[2], y[6]);
    v2f t3 = pkadd(y[3], y[7]), t7 = pkw83(pksub(y[3], y[7]));
    v2f u0 = pkadd(t0, t2), u2 = pksub(t0, t2);
    v2f u1 = pkadd(t1, t3), w13 = pksub(t1, t3);
    v2f v0 = pkaddi(t4, d26), v2 = pksubi(t4, d26);
    v2f v1 = pkadd(t5, t7), w57 = pksub(t5, t7);
    o[0] = pkaddi(u2, w13);    // Y2
    o[1] = pkaddi(v2, w57);    // Y3
    o[2] = pksub(u0, u1);      // Y4
    o[3] = pksub(v0, v1);      // Y5
}

// W512^m from half-table
__device__ __forceinline__ v2f wlookup(const float2* trig, int m) {
    m &= 511;
    float2 ph = trig[m & 255];
    return (m & 256) ? v2f{-ph.x, -ph.y} : v2f{ph.x, ph.y};
}

// ---- in-register lane exchanges (transpose building blocks) -------------------------------------
template<int CTRL>
__device__ __forceinline__ float dppx(float x) {
    return __int_as_float(__builtin_amdgcn_mov_dpp(__float_as_int(x), CTRL, 0xF, 0xF, true));
}
__device__ __forceinline__ float swzx4(float x) {
    // BitMode swizzle: and=0x1F, or=0, xor=4  -> lane ^ 4
    return __int_as_float(__builtin_amdgcn_ds_swizzle(__float_as_int(x), 0x101F));
}

// Batched xor1 stage over pairs (G0,G1)(G2,G3)(G4,G5)(G6,G7): vcc loaded ONCE per side.
// a' = (L&1) ? b[L^1] : a  -> dst = vcc(kA=even-lanes) ? a : dpp(b), quad_perm:[1,0,3,2]
// b' = (L&1) ? b : a[L^1]  -> dst = vcc(kB=odd-lanes)  ? b : dpp(a)
__device__ __forceinline__ void xor1_stage(v2f G[8],
                                           unsigned long long kA, unsigned long long kB) {
    v2f n0, n1, n2, n3, m0, m1, m2, m3;
    asm("s_mov_b64 vcc, %[k]\n\t"
        "s_nop 0\n\t"
        "v_cndmask_b32_dpp %[o0], %[s0], %[t0], vcc quad_perm:[1,0,3,2] row_mask:0xf bank_mask:0xf\n\t"
        "v_cndmask_b32_dpp %[o1], %[s1], %[t1], vcc quad_perm:[1,0,3,2] row_mask:0xf bank_mask:0xf\n\t"
        "v_cndmask_b32_dpp %[o2], %[s2], %[t2], vcc quad_perm:[1,0,3,2] row_mask:0xf bank_mask:0xf\n\t"
        "v_cndmask_b32_dpp %[o3], %[s3], %[t3], vcc quad_perm:[1,0,3,2] row_mask:0xf bank_mask:0xf\n\t"
        "v_cndmask_b32_dpp %[o4], %[s4], %[t4], vcc quad_perm:[1,0,3,2] row_mask:0xf bank_mask:0xf\n\t"
        "v_cndmask_b32_dpp %[o5], %[s5], %[t5], vcc quad_perm:[1,0,3,2] row_mask:0xf bank_mask:0xf\n\t"
        "v_cndmask_b32_dpp %[o6], %[s6], %[t6], vcc quad_perm:[1,0,3,2] row_mask:0xf bank_mask:0xf\n\t"
        "v_cndmask_b32_dpp %[o7], %[s7], %[t7], vcc quad_perm:[1,0,3,2] row_mask:0xf bank_mask:0xf"
        : [o0]"=&v"(n0.x), [o1]"=&v"(n0.y), [o2]"=&v"(n1.x), [o3]"=&v"(n1.y),
          [o4]"=&v"(n2.x), [o5]"=&v"(n2.y), [o6]"=&v"(n3.x), [o7]"=&v"(n3.y)
        : [s0]"v"(G[1].x), [t0]"v"(G[0].x), [s1]"v"(G[1].y), [t1]"v"(G[0].y),
          [s2]"v"(G[3].x), [t2]"v"(G[2].x), [s3]"v"(G[3].y), [t3]"v"(G[2].y),
          [s4]"v"(G[5].x), [t4]"v"(G[4].x), [s5]"v"(G[5].y), [t5]"v"(G[4].y),
          [s6]"v"(G[7].x), [t6]"v"(G[6].x), [s7]"v"(G[7].y), [t7]"v"(G[6].y),
          [k]"s"(kA)
        : "vcc");
    asm("s_mov_b64 vcc, %[k]\n\t"
        "s_nop 0\n\t"
        "v_cndmask_b32_dpp %[o0], %[s0], %[t0], vcc quad_perm:[1,0,3,2] row_mask:0xf bank_mask:0xf\n\t"
        "v_cndmask_b32_dpp %[o1], %[s1], %[t1], vcc quad_perm:[1,0,3,2] row_mask:0xf bank_mask:0xf\n\t"
        "v_cndmask_b32_dpp %[o2], %[s2], %[t2], vcc quad_perm:[1,0,3,2] row_mask:0xf bank_mask:0xf\n\t"
        "v_cndmask_b32_dpp %[o3], %[s3], %[t3], vcc quad_perm:[1,0,3,2] row_mask:0xf bank_mask:0xf\n\t"
        "v_cndmask_b32_dpp %[o4], %[s4], %[t4], vcc quad_perm:[1,0,3,2] row_mask:0xf bank_mask:0xf\n\t"
        "v_cndmask_b32_dpp %[o5], %[s5], %[t5], vcc quad_perm:[1,0,3,2] row_mask:0xf bank_mask:0xf\n\t"
        "v_cndmask_b32_dpp %[o6], %[s6], %[t6], vcc quad_perm:[1,0,3,2] row_mask:0xf bank_mask:0xf\n\t"
        "v_cndmask_b32_dpp %[o7], %[s7], %[t7], vcc quad_perm:[1,0,3,2] row_mask:0xf bank_mask:0xf"
        : [o0]"=&v"(m0.x), [o1]"=&v"(m0.y), [o2]"=&v"(m1.x), [o3]"=&v"(m1.y),
          [o4]"=&v"(m2.x), [o5]"=&v"(m2.y), [o6]"=&v"(m3.x), [o7]"=&v"(m3.y)
        : [s0]"v"(G[0].x), [t0]"v"(G[1].x), [s1]"v"(G[0].y), [t1]"v"(G[1].y),
          [s2]"v"(G[2].x), [t2]"v"(G[3].x), [s3]"v"(G[2].y), [t3]"v"(G[3].y),
          [s4]"v"(G[4].x), [t4]"v"(G[5].x), [s5]"v"(G[4].y), [t5]"v"(G[5].y),
          [s6]"v"(G[6].x), [t6]"v"(G[7].x), [s7]"v"(G[6].y), [t7]"v"(G[7].y),
          [k]"s"(kB)
        : "vcc");
    G[0] = n0; G[1] = m0; G[2] = n1; G[3] = m1;
    G[4] = n2; G[5] = m2; G[6] = n3; G[7] = m3;
}

// Batched xor2 stage over pairs (G0,G2)(G1,G3)(G4,G6)(G5,G7), quad_perm:[2,3,0,1].
__device__ __forceinline__ void xor2_stage(v2f G[8],
                                           unsigned long long kA, unsigned long long kB) {
    v2f n0, n1, n2, n3, m0, m1, m2, m3;
    asm("s_mov_b64 vcc, %[k]\n\t"
        "s_nop 0\n\t"
        "v_cndmask_b32_dpp %[o0], %[s0], %[t0], vcc quad_perm:[2,3,0,1] row_mask:0xf bank_mask:0xf\n\t"
        "v_cndmask_b32_dpp %[o1], %[s1], %[t1], vcc quad_perm:[2,3,0,1] row_mask:0xf bank_mask:0xf\n\t"
        "v_cndmask_b32_dpp %[o2], %[s2], %[t2], vcc quad_perm:[2,3,0,1] row_mask:0xf bank_mask:0xf\n\t"
        "v_cndmask_b32_dpp %[o3], %[s3], %[t3], vcc quad_perm:[2,3,0,1] row_mask:0xf bank_mask:0xf\n\t"
        "v_cndmask_b32_dpp %[o4], %[s4], %[t4], vcc quad_perm:[2,3,0,1] row_mask:0xf bank_mask:0xf\n\t"
        "v_cndmask_b32_dpp %[o5], %[s5], %[t5], vcc quad_perm:[2,3,0,1] row_mask:0xf bank_mask:0xf\n\t"
        "v_cndmask_b32_dpp %[o6], %[s6], %[t6], vcc quad_perm:[2,3,0,1] row_mask:0xf bank_mask:0xf\n\t"
        "v_cndmask_b32_dpp %[o7], %[s7], %[t7], vcc quad_perm:[2,3,0,1] row_mask:0xf bank_mask:0xf"
        : [o0]"=&v"(n0.x), [o1]"=&v"(n0.y), [o2]"=&v"(n1.x), [o3]"=&v"(n1.y),
          [o4]"=&v"(n2.x), [o5]"=&v"(n2.y), [o6]"=&v"(n3.x), [o7]"=&v"(n3.y)
        : [s0]"v"(G[2].x), [t0]"v"(G[0].x), [s1]"v"(G[2].y), [t1]"v"(G[0].y),
          [s2]"v"(G[3].x), [t2]"v"(G[1].x), [s3]"v"(G[3].y), [t3]"v"(G[1].y),
          [s4]"v"(G[6].x), [t4]"v"(G[4].x), [s5]"v"(G[6].y), [t5]"v"(G[4].y),
          [s6]"v"(G[7].x), [t6]"v"(G[5].x), [s7]"v"(G[7].y), [t7]"v"(G[5].y),
          [k]"s"(kA)
        : "vcc");
    asm("s_mov_b64 vcc, %[k]\n\t"
        "s_nop 0\n\t"
        "v_cndmask_b32_dpp %[o0], %[s0], %[t0], vcc quad_perm:[2,3,0,1] row_mask:0xf bank_mask:0xf\n\t"
        "v_cndmask_b32_dpp %[o1], %[s1], %[t1], vcc quad_perm:[2,3,0,1] row_mask:0xf bank_mask:0xf\n\t"
        "v_cndmask_b32_dpp %[o2], %[s2], %[t2], vcc quad_perm:[2,3,0,1] row_mask:0xf bank_mask:0xf\n\t"
        "v_cndmask_b32_dpp %[o3], %[s3], %[t3], vcc quad_perm:[2,3,0,1] row_mask:0xf bank_mask:0xf\n\t"
        "v_cndmask_b32_dpp %[o4], %[s4], %[t4], vcc quad_perm:[2,3,0,1] row_mask:0xf bank_mask:0xf\n\t"
        "v_cndmask_b32_dpp %[o5], %[s5], %[t5], vcc quad_perm:[2,3,0,1] row_mask:0xf bank_mask:0xf\n\t"
        "v_cndmask_b32_dpp %[o6], %[s6], %[t6], vcc quad_perm:[2,3,0,1] row_mask:0xf bank_mask:0xf\n\t"
        "v_cndmask_b32_dpp %[o7], %[s7], %[t7], vcc quad_perm:[2,3,0,1] row_mask:0xf bank_mask:0xf"
        : [o0]"=&v"(m0.x), [o1]"=&v"(m0.y), [o2]"=&v"(m1.x), [o3]"=&v"(m1.y),
          [o4]"=&v"(m2.x), [o5]"=&v"(m2.y), [o6]"=&v"(m3.x), [o7]"=&v"(m3.y)
        : [s0]"v"(G[0].x), [t0]"v"(G[2].x), [s1]"v"(G[0].y), [t1]"v"(G[2].y),
          [s2]"v"(G[1].x), [t2]"v"(G[3].x), [s3]"v"(G[1].y), [t3]"v"(G[3].y),
          [s4]"v"(G[4].x), [t4]"v"(G[6].x), [s5]"v"(G[4].y), [t5]"v"(G[6].y),
          [s6]"v"(G[5].x), [t6]"v"(G[7].x), [s7]"v"(G[5].y), [t7]"v"(G[7].y),
          [k]"s"(kB)
        : "vcc");
    G[0] = n0; G[2] = m0; G[1] = n1; G[3] = m1;
    G[4] = n2; G[6] = m2; G[5] = n3; G[7] = m3;
}

#if __has_builtin(__builtin_amdgcn_update_dpp)
// xor4 exchange via masked-merge DPP (lane^4 stays within a 16-lane row).
// Convention (verified R27): row_ror:N -> dst lane i reads src (i-N)%16.
//   a' : banks 1,3 (L&4!=0) need b[L-4] -> row_ror:4  (0x124), bank_mask 0xA
//   b' : banks 0,2 (L&4==0) need a[L+4] -> row_ror:12 (0x12C), bank_mask 0x5
__device__ __forceinline__ void xchg4(v2f& a, v2f& b, bool /*bit*/) {
    int ax = __float_as_int(a.x), ay = __float_as_int(a.y);
    int bx = __float_as_int(b.x), by = __float_as_int(b.y);
    a.x = __int_as_float(__builtin_amdgcn_update_dpp(ax, bx, 0x124, 0xF, 0xA, false));
    a.y = __int_as_float(__builtin_amdgcn_update_dpp(ay, by, 0x124, 0xF, 0xA, false));
    b.x = __int_as_float(__builtin_amdgcn_update_dpp(bx, ax, 0x12C, 0xF, 0x5, false));
    b.y = __int_as_float(__builtin_amdgcn_update_dpp(by, ay, 0x12C, 0xF, 0x5, false));
}
// xor8 exchange via masked-merge DPP: row_ror:8 (self-inverse, direction-agnostic);
// bank_mask 0xC = lanes (L&8)!=0, 0x3 = rest. HW-validated since R21.
__device__ __forceinline__ void xchg8(v2f& a, v2f& b, bool /*bit*/) {
    int ax = __float_as_int(a.x), ay = __float_as_int(a.y);
    int bx = __float_as_int(b.x), by = __float_as_int(b.y);
    a.x = __int_as_float(__builtin_amdgcn_update_dpp(ax, bx, 0x128, 0xF, 0xC, false));
    a.y = __int_as_float(__builtin_amdgcn_update_dpp(ay, by, 0x128, 0xF, 0xC, false));
    b.x = __int_as_float(__builtin_amdgcn_update_dpp(bx, ax, 0x128, 0xF, 0x3, false));
    b.y = __int_as_float(__builtin_amdgcn_update_dpp(by, ay, 0x128, 0xF, 0x3, false));
}
#else
__device__ __forceinline__ void xchg4(v2f& a, v2f& b, bool bit) {
    float dbx = swzx4(b.x);
    float dby = swzx4(b.y);
    float dax = swzx4(a.x);
    float day = swzx4(a.y);
    a.x = bit ? dbx : a.x;   a.y = bit ? dby : a.y;
    b.x = bit ? b.x : dax;   b.y = bit ? b.y : day;
}
__device__ __forceinline__ void xchg8(v2f& a, v2f& b, bool bit) {
    float dbx = dppx<0x128>(b.x);
    float dby = dppx<0x128>(b.y);
    float dax = dppx<0x128>(a.x);
    float day = dppx<0x128>(a.y);
    a.x = bit ? dbx : a.x;   a.y = bit ? dby : a.y;
    b.x = bit ? b.x : dax;   b.y = bit ? b.y : day;
}
#endif

#if __has_builtin(__builtin_amdgcn_permlane16_swap)
__device__ __forceinline__ void pl16x(v2f& a, v2f& b) {
    v2u rx = __builtin_amdgcn_permlane16_swap(__float_as_uint(a.x), __float_as_uint(b.x), false, false);
    a.x = __uint_as_float(rx.x); b.x = __uint_as_float(rx.y);
    v2u ry = __builtin_amdgcn_permlane16_swap(__float_as_uint(a.y), __float_as_uint(b.y), false, false);
    a.y = __uint_as_float(ry.x); b.y = __uint_as_float(ry.y);
}
#else
__device__ __forceinline__ void pl16x(v2f& a, v2f& b) {
    bool bit = (threadIdx.x & 16) != 0;
    float sx = bit ? a.x : b.x, sy = bit ? a.y : b.y;
    float tx = __shfl_xor(sx, 16), ty = __shfl_xor(sy, 16);
    a.x = bit ? tx : a.x; a.y = bit ? ty : a.y;
    b.x = bit ? b.x : tx; b.y = bit ? b.y : ty;
}
#endif

#if __has_builtin(__builtin_amdgcn_permlane32_swap)
__device__ __forceinline__ void pl32x(v2f& a, v2f& b) {
    v2u rx = __builtin_amdgcn_permlane32_swap(__float_as_uint(a.x), __float_as_uint(b.x), false, false);
    a.x = __uint_as_float(rx.x); b.x = __uint_as_float(rx.y);
    v2u ry = __builtin_amdgcn_permlane32_swap(__float_as_uint(a.y), __float_as_uint(b.y), false, false);
    a.y = __uint_as_float(ry.x); b.y = __uint_as_float(ry.y);
}
#else
__device__ __forceinline__ void pl32x(v2f& a, v2f& b) {
    bool bit = (threadIdx.x & 32) != 0;
    float sx = bit ? a.x : b.x, sy = bit ? a.y : b.y;
    float tx = __shfl_xor(sx, 32), ty = __shfl_xor(sy, 32);
    a.x = bit ? tx : a.x; a.y = bit ? ty : a.y;
    b.x = bit ? b.x : tx; b.y = bit ? b.y : ty;
}
#endif

// hot-loop step: in-register 512-pt inverse DFT (8x8x8 four-step; transposes via
// permlane/DPP), publish G2..G5 to this step's parity buffer, ONE barrier, gather.
// awBase/ldsBase carry the parity offset (0 or 32) folded in by the caller.
__device__ __forceinline__ void fft_sample(
    const v2f y[8], const v2f tA[8], const v2f tB[8],
    bool b2, bool b3,
    char* awBase, const char* ldsBase, int spos, const v2f ph[RPB], bool active,
    float* pA)
{
    const unsigned long long K1A = 0x5555555555555555ULL;  // (L&1)==0
    const unsigned long long K1B = 0xAAAAAAAAAAAAAAAAULL;
    const unsigned long long K2A = 0x3333333333333333ULL;  // (L&2)==0
    const unsigned long long K2B = 0xCCCCCCCCCCCCCCCCULL;
    v2f G[8];
    dft8p(y, G);                                   // DFT over q2 (reg digit) -> v0
#pragma unroll
    for (int k1 = 1; k1 < 8; ++k1) G[k1] = cmulv(G[k1], tA[k1]);   // W512^{L*v0}
    // T1: reg digit (v0) <-> lane-high digit (q1)
    xchg8(G[0], G[1], b3);  xchg8(G[2], G[3], b3);                       // xor8 (merge-DPP)
    xchg8(G[4], G[5], b3);  xchg8(G[6], G[7], b3);
    pl16x(G[0], G[2]);  pl16x(G[1], G[3]);  pl16x(G[4], G[6]);  pl16x(G[5], G[7]);   // xor16
    pl32x(G[0], G[4]);  pl32x(G[1], G[5]);  pl32x(G[2], G[6]);  pl32x(G[3], G[7]);   // xor32
    dft8p_ip(G);                                   // DFT over q1 -> v1
#pragma unroll
    for (int m1 = 1; m1 < 8; ++m1) G[m1] = cmulv(G[m1], tB[m1]);   // W512^{8*q0*v1}
    // T2: reg digit (v1) <-> lane-low digit (q0); batched vcc loads
    xor1_stage(G, K1A, K1B);                                             // cndmask_dpp xor1
    xor2_stage(G, K2A, K2B);                                             // cndmask_dpp xor2
    xchg4(G[0], G[4], b2);  xchg4(G[1], G[5], b2);                       // xor4 (merge-DPP)
    xchg4(G[2], G[6], b2);  xchg4(G[3], G[7], b2);
    v2f o[4];
    dft8p_mid4(G, o);                              // DFT over q0 -> v2 (only outputs 2..5)
    *(v4f*)(awBase +  0) = v4f{o[0].x, o[0].y, o[1].x, o[1].y};   // G2,G3
    *(v4f*)(awBase + 16) = v4f{o[2].x, o[2].y, o[3].x, o[3].y};   // G4,G5
    __syncthreads();   // single barrier: publish visible; orders prev gather vs buffer reuse
    if (active) {
        v2f accv = v2f{0.0f, 0.0f};
#pragma unroll
        for (int ww = 0; ww < RPB; ++ww) {
            v2f q = *(const v2f*)(ldsBase + ww * WREG + spos);
            // accv += {q.x*ph.x, -q.y*ph.y}
            asm("v_pk_fma_f32 %0, %1, %2, %0 neg_hi:[1,0,0]" : "+v"(accv) : "v"(q), "v"(ph[ww]));
        }
        pA[0] = accv.x + accv.y;
    }
}

// ---------------- init kernels (run once, shuffle FFT; cold path stays scalar) -------------------
__device__ __forceinline__ void cbfly(float& ar, float& ai, float& br, float& bi,
                                      float wr, float wi) {
    float dr = ar - br, di = ai - bi;
    ar = ar + br; ai = ai + bi;
    br = fmaf(dr, wr, -di * wi);
    bi = fmaf(dr, wi,  di * wr);
}

__device__ __forceinline__ void init_trig(float2* trig, int tid) {
    if (tid < 256) {
        float ang = (float)tid * (6.283185307179586f / 512.0f);
        float s, c;
        sincosf(ang, &s, &c);
        trig[tid] = make_float2(c, s);
    }
}

__device__ __forceinline__ void fft512_inv_lds(float* xr, float* xi, const float2* trig, int L) {
#pragma unroll
    for (int r = 0; r < 4; ++r) {
        float2 w = trig[(r << 6) + L];
        cbfly(xr[r], xi[r], xr[r + 4], xi[r + 4], w.x, w.y);
    }
    {
        float2 w0 = trig[L << 1];
        float2 w1 = trig[(64 + L) << 1];
        cbfly(xr[0], xi[0], xr[2], xi[2], w0.x, w0.y);
        cbfly(xr[1], xi[1], xr[3], xi[3], w1.x, w1.y);
        cbfly(xr[4], xi[4], xr[6], xi[6], w0.x, w0.y);
        cbfly(xr[5], xi[5], xr[7], xi[7], w1.x, w1.y);
    }
    {
        float2 w = trig[L << 2];
        cbfly(xr[0], xi[0], xr[1], xi[1], w.x, w.y);
        cbfly(xr[2], xi[2], xr[3], xi[3], w.x, w.y);
        cbfly(xr[4], xi[4], xr[5], xi[5], w.x, w.y);
        cbfly(xr[6], xi[6], xr[7], xi[7], w.x, w.y);
    }
#pragma unroll
    for (int s = 3; s <= 8; ++s) {
        const int half = 512 >> (s + 1);
        const int ex = (L & (half - 1)) << s;
        float2 w = trig[ex];
        const bool hi = (L & half) != 0;
        float wr = hi ? w.x : 1.0f;
        float wi = hi ? w.y : 0.0f;
        float sg = hi ? -1.0f : 1.0f;
#pragma unroll
        for (int r = 0; r < 8; ++r) {
            float orv = __shfl_xor(xr[r], half);
            float oiv = __shfl_xor(xi[r], half);
            float tr = fmaf(sg, xr[r], orv);
            float ti = fmaf(sg, xi[r], oiv);
            xr[r] = fmaf(tr, wr, -ti * wi);
            xi[r] = fmaf(tr, wi,  ti * wr);
        }
    }
}

__global__ __launch_bounds__(256) void f1_kernel(const float* __restrict__ f,
                                                 float2* __restrict__ R) {
    __shared__ float2 trig[256];
    const int tid = threadIdx.x;
    init_trig(trig, tid);
    __syncthreads();
    const int w = tid >> 6, L = tid & 63;
    const int x = 128 + blockIdx.x * 4 + w;   // nonzero rows only: [128, 384)
    const int b = blockIdx.y;
    const float* frow = f + ((size_t)b * 256 + (x - 128)) * 256;
    float xr[8], xi[8];
#pragma unroll
    for (int r = 0; r < 8; ++r) {
        int e = r * 64 + L;
        xr[r] = (e >= 128 && e < 384) ? frow[e - 128] : 0.0f;
        xi[r] = 0.0f;
    }
    fft512_inv_lds(xr, xi, trig, L);
    float2* Rrow = R + ((size_t)b * NOUT + x) * NOUT;
#pragma unroll
    for (int r = 0; r < 8; ++r) {
        int e = r * 64 + L;
        int k = __brev((unsigned)e) >> 23;
        Rrow[k] = make_float2(xr[r], -xi[r]);
    }
}

// f2: rows x outside [128,384) of R were never written (and are not zeroed) — treat as 0.
// e = r*64 + L is in [128,384) exactly for r in [2,6).
__global__ __launch_bounds__(256) void f2_kernel(const float2* __restrict__ R,
                                                 float2* __restrict__ A0) {
    __shared__ float2 trig[256];
    const int tid = threadIdx.x;
    init_trig(trig, tid);
    __syncthreads();
    const int w = tid >> 6, L = tid & 63;
    const int q = blockIdx.x * 4 + w;
    const int b = blockIdx.y;
    float xr[8], xi[8];
#pragma unroll
    for (int r = 0; r < 8; ++r) {
        if (r >= 2 && r < 6) {
            int e = r * 64 + L;
            float2 v = R[((size_t)b * NOUT + e) * NOUT + q];
            xr[r] = v.x;
            xi[r] = -v.y;
        } else {
            xr[r] = 0.0f;
            xi[r] = 0.0f;
        }
    }
    fft512_inv_lds(xr, xi, trig, L);
#pragma unroll
    for (int r = 0; r < 8; ++r) {
        int e = r * 64 + L;
        int p = __brev((unsigned)e) >> 23;
        A0[((size_t)b * NOUT + p) * NOUT + q] = make_float2(xr[r], -xi[r]);
    }
}

// ---------------- time-chunk simulation ----------------------------------------------------------
// block = (row group g of RPB rows, batch b); wave w owns row p = RPB*g + w, p in 0..257.
// Threads 0..255 each own one sensor, summing the block's RPB rows after the step barrier.
__global__ __launch_bounds__(384, 4) void sim_kernel(
    const float* __restrict__ fil,
    const int* __restrict__ idx0, const int* __restrict__ idx1,
    float2* __restrict__ stateCur, float2* __restrict__ statePrev,
    float* __restrict__ partial, int Tc, int firstChunk, int lastChunk)
{
    __shared__ __align__(16) char waveMem[RPB * WREG];   // 31104 B
    __shared__ float2 trig[256];                         //  2048 B -> 33152 B total

    const int tid = threadIdx.x;              // 0..383
    const int w = tid >> 6, L = tid & 63;
    const int g = blockIdx.x, b = blockIdx.y;
    const int p = g * RPB + w;                // 0..257

    if (tid < 256) {
        float ang = (float)tid * (6.283185307179586f / 512.0f);
        float s, c;
        sincosf(ang, &s, &c);
        trig[tid] = make_float2(c, s);
    }
    __syncthreads();

    // --- per-lane constant twiddles ---
    v2f tA[8], tB[8];
#pragma unroll
    for (int k1 = 1; k1 < 8; ++k1) tA[k1] = wlookup(trig, L * k1);
#pragma unroll
    for (int m1 = 1; m1 < 8; ++m1) tB[m1] = wlookup(trig, 8 * (L & 7) * m1);

    // --- transpose predicates (loop-invariant; used by fallback paths) ---
    const bool b2 = (L & 4) != 0;
    const bool b3 = (L & 8) != 0;

    // --- sensor constants: thread tid<256 owns sensor j=tid ---
    const bool active = tid < 256;
    int spos = 0;
    v2f ph[RPB];
    if (active) {
        int u = idx0[tid];
        int v = idx1[tid];
        // published regs are v>>6 in {2..5} at lane-local offsets 0,8,16,24 (parity 0)
        spos = ((v & 7) * 8 + ((v >> 3) & 7)) * 80 + ((v >> 6) * 8 - 16);
        // Hermitian fold phase: p==0 -> 1, p==256 -> (-1)^u, p==257 -> 0, else 2*W512^{pu}
#pragma unroll
        for (int ww = 0; ww < RPB; ++ww) {
            int prow = g * RPB + ww;
            v2f a0;
            if (prow == 0)        a0 = v2f{1.0f, 0.0f};
            else if (prow == 256) a0 = v2f{(u & 1) ? -1.0f : 1.0f, 0.0f};
            else if (prow == 257) a0 = v2f{0.0f, 0.0f};
            else                  a0 = 2.0f * wlookup(trig, prow * u);
            ph[ww] = a0;
        }
    } else {
#pragma unroll
        for (int ww = 0; ww < RPB; ++ww) ph[ww] = v2f{0.0f, 0.0f};
    }

    // --- per-lane LDS publish base; parity buffer offsets 0 / 32 within the pitch-80 slot ---
    char* myA    = waveMem + w * WREG;
    char* awBase = myA + L * 80;

    // --- load state + filter into registers ---
    v2f a[8], bb[8];
    float C[8];
    {
        const size_t rowBase = ((size_t)b * NOUT + p) * NOUT;
        const float* filRow = fil + (size_t)p * NOUT;
#pragma unroll
        for (int r = 0; r < 8; ++r) {
            int e = r * 64 + L;
            float2 a0 = stateCur[rowBase + e];
            a[r] = v2f{a0.x, a0.y};
            if (firstChunk) {
                bb[r] = a[r];
            } else {
                float2 a1 = statePrev[rowBase + e];
                bb[r] = v2f{a1.x, a1.y};
            }
            C[r] = fmaf(-4.0f, filRow[e], 2.0f);
        }
    }

    float* pOut = partial + ((size_t)g * Tc * NB + b) * NPHI + tid;

    for (int tl = 0; tl < Tc; tl += 2) {
        // step A (parity 0): bb becomes A_{t+1}
#pragma unroll
        for (int r = 0; r < 8; ++r) bb[r] = v2f{C[r], C[r]} * a[r] - bb[r];
        fft_sample(bb, tA, tB, b2, b3, awBase, waveMem,
                   spos, ph, active, pOut);
        pOut += NB * NPHI;
        // step B (parity 1): a becomes A_{t+2}
#pragma unroll
        for (int r = 0; r < 8; ++r) a[r] = v2f{C[r], C[r]} * bb[r] - a[r];
        fft_sample(a, tA, tB, b2, b3, awBase + 32, waveMem + 32,
                   spos, ph, active, pOut);
        pOut += NB * NPHI;
    }

    // --- save state for the next chunk (skipped when this is the last chunk) ---
    if (!lastChunk) {
        const size_t rowBase = ((size_t)b * NOUT + p) * NOUT;
#pragma unroll
        for (int r = 0; r < 8; ++r) {
            int e = r * 64 + L;
            stateCur[rowBase + e]  = make_float2(a[r].x, a[r].y);
            statePrev[rowBase + e] = make_float2(bb[r].x, bb[r].y);
        }
    }
}

// ---------------- reduce NGRP row-group partials -> out[b][j][t] ----------------------------------
__global__ __launch_bounds__(256) void reduce_kernel(const float* __restrict__ partial,
                                                     float* __restrict__ out,
                                                     int Tc, int tStart) {
    int id = blockIdx.x * 256 + threadIdx.x;   // over Tc*16*256, exact
    int j = id & 255;
    int b = (id >> 8) & 15;
    int tl = id >> 12;
    float s = 0.0f;
#pragma unroll
    for (int gg = 0; gg < NGRP; ++gg)
        s += partial[(((size_t)gg * Tc + tl) * NB + b) * NPHI + j];
    out[((size_t)b * NPHI + j) * NT + (tStart + tl)] = s * (1.0f / (512.0f * 512.0f));
}

extern "C" void kernel_launch(void* const* d_in, const int* in_sizes, int n_in,
                              void* d_out, int out_size, void* d_ws, size_t ws_size,
                              hipStream_t stream) {
    (void)in_sizes; (void)n_in; (void)out_size;
    const float* f   = (const float*)d_in[0];   // [16,1,256,256]
    const float* fil = (const float*)d_in[1];   // [512,512]
    const int* idx0  = (const int*)d_in[2];     // [256]
    const int* idx1  = (const int*)d_in[3];     // [256]
    float* out = (float*)d_out;                 // [16,1,256,240]

    char* ws = (char*)d_ws;
    const size_t stateBytes = (size_t)NB * NOUT * NOUT * sizeof(float2);  // 33.55 MB
    float2* stateCur  = (float2*)ws;
    float2* statePrev = (float2*)(ws + stateBytes);   // also reused as R scratch for f1/f2
    float*  partial   = (float*)(ws + 2 * stateBytes);
    size_t remain = (ws_size > 2 * stateBytes) ? ws_size - 2 * stateBytes : 0;

    // largest even time chunk whose partial buffer fits (even: the sim loop is 2-step unrolled)
    static const int tcs[] = {240, 120, 80, 60, 48, 40, 30, 24, 20, 16, 12, 10, 8, 6, 4, 2};
    int Tc = 2;
    for (int i = 0; i < 16; ++i) {
        size_t need = (size_t)NGRP * tcs[i] * NB * NPHI * sizeof(float);
        if (need <= remain) { Tc = tcs[i]; break; }
    }

    // no memset: f1 writes rows [128,384) of the R scratch; f2 skips the rest as known-zero
    f1_kernel<<<dim3(64, NB), 256, 0, stream>>>(f, statePrev);        // rows x in [128,384)
    f2_kernel<<<dim3(128, NB), 256, 0, stream>>>(statePrev, stateCur);
    for (int t0 = 0; t0 < NT; t0 += Tc) {
        int last = (t0 + Tc) >= NT ? 1 : 0;
        sim_kernel<<<dim3(NGRP, NB), RPB * 64, 0, stream>>>(fil, idx0, idx1, stateCur, statePrev,
                                                            partial, Tc, t0 == 0 ? 1 : 0, last);
        reduce_kernel<<<dim3(Tc * NB), 256, 0, stream>>>(partial, out, Tc, t0);
    }
}

// Round 13
// 782.895 us; speedup vs baseline: 1.1370x; 1.1370x over previous
//
#include <hip/hip_runtime.h>
#include <hip/hip_bf16.h>

// WaveOperator: Fourier-domain 3-term recurrence + per-row inverse FFT sampling.
// A_{t+1}(p,q) = (2-4*fil(p,q)) * A_t - A_{t-1};  y[b,j,t] = Re(ifft2(A_{t+1})[u_j,v_j])
// R29 = R27 verbatim (session best: 719us sim / 782.7us total; session start was 990us).
// R28 post-mortem: batching the xor1/xor2 vcc loads into monolithic 8-op asm blocks forced
// 24 simultaneously-live VGPRs per block + removed scheduling freedom -> copies and stalls
// (VALUBusy 57->48.8%, sim 719->827). The per-exchange asm granularity of R25/R27 is optimal.
// Ladder: R18 transposes off LDS (+2.5%), R19 publish halving, R23 fusable exchange forms
// (+4%), R24 VOP3P packed DFT/twiddles (+11%), R25 cndmask_dpp xor1/2 (+6%), R27 xor4
// merge-DPP (+1.3%). Falsified: ILP dual-chain (R20), twiddle precompute (R21), gather
// balance (R22), vcc batching (R28) -- allocator pins VGPR=64, spills any added live state.
// Remaining: dependency-latency floor of the serial FFT chain at ~57% VALU issue; conflicts
// 1.71e7 (~4%, scattered sensor gather, irreducible); HBM 3%; occupancy at natural 3-blk/CU.

#define NOUT 512
#define NB 16
#define NPHI 256
#define NT 240
#define RPB 6             // rows per block (= waves per block)
#define NGRP 43           // row groups: 43*6 = 258 = rows 0..257 (257 gets zero phase)

#define WREG 5184         // per-wave LDS publish region (pitch 80; lane uses 2x32B parity bufs)

typedef float v2f __attribute__((ext_vector_type(2)));
typedef float v4f __attribute__((ext_vector_type(4)));
typedef unsigned int v2u __attribute__((ext_vector_type(2)));

// ---- VOP3P packed-fp32 primitives (register-neutral; modifiers do the swizzles) -----------------
__device__ __forceinline__ v2f pkadd(v2f a, v2f b) {
    v2f d; asm("v_pk_add_f32 %0, %1, %2" : "=v"(d) : "v"(a), "v"(b)); return d;
}
__device__ __forceinline__ v2f pksub(v2f a, v2f b) {
    v2f d; asm("v_pk_add_f32 %0, %1, %2 neg_lo:[0,1] neg_hi:[0,1]" : "=v"(d) : "v"(a), "v"(b)); return d;
}
// a + i*w = {a.x - w.y, a.y + w.x}
__device__ __forceinline__ v2f pkaddi(v2f a, v2f w) {
    v2f d; asm("v_pk_add_f32 %0, %1, %2 op_sel:[0,1] op_sel_hi:[1,0] neg_lo:[0,1]"
               : "=v"(d) : "v"(a), "v"(w)); return d;
}
// a - i*w = {a.x + w.y, a.y - w.x}
__device__ __forceinline__ v2f pksubi(v2f a, v2f w) {
    v2f d; asm("v_pk_add_f32 %0, %1, %2 op_sel:[0,1] op_sel_hi:[1,0] neg_hi:[0,1]"
               : "=v"(d) : "v"(a), "v"(w)); return d;
}
// s * {a.x - a.y, a.x + a.y}   (w8 twiddle)
__device__ __forceinline__ v2f pkw8(v2f a) {
    v2f d; asm("v_pk_add_f32 %0, %1, %1 op_sel:[0,1] op_sel_hi:[0,1] neg_lo:[0,1]"
               : "=v"(d) : "v"(a));
    const float s = 0.70710678118654752f;
    return v2f{s * d.x, s * d.y};
}
// {-s*(a.x + a.y), s*(a.x - a.y)}   (w8^3 twiddle)
__device__ __forceinline__ v2f pkw83(v2f a) {
    v2f d; asm("v_pk_add_f32 %0, %1, %1 op_sel:[0,1] op_sel_hi:[0,1] neg_hi:[0,1]"
               : "=v"(d) : "v"(a));
    const float s = 0.70710678118654752f;
    return v2f{-s * d.x, s * d.y};
}
// complex mul g*t: {g.x*t.x - g.y*t.y, g.x*t.y + g.y*t.x} in 2 VOP3P ops
__device__ __forceinline__ v2f cmulv(v2f g, v2f t) {
    v2f p, d;
    asm("v_pk_mul_f32 %0, %1, %2 op_sel:[0,0] op_sel_hi:[0,1]" : "=v"(p) : "v"(g), "v"(t));
    // p = {g.x*t.x, g.x*t.y}
    asm("v_pk_fma_f32 %0, %1, %2, %3 op_sel:[1,1,0] op_sel_hi:[1,0,1] neg_lo:[1,0,0]"
        : "=v"(d) : "v"(g), "v"(t), "v"(p));
    // d = {-g.y*t.y + p.x, g.y*t.x + p.y}
    return d;
}

// 8-pt DFT, positive exponent: Y[k] = sum_r y[r] * exp(+2pi i rk/8)  (packed form)
__device__ __forceinline__ void dft8p(const v2f y[8], v2f Y[8]) {
    v2f t0 = pkadd(y[0], y[4]), t4 = pksub(y[0], y[4]);
    v2f t1 = pkadd(y[1], y[5]), t5 = pkw8(pksub(y[1], y[5]));
    v2f t2 = pkadd(y[2], y[6]), d26 = pksub(y[2], y[6]);   // t6 = i*d26 folded into consumers
    v2f t3 = pkadd(y[3], y[7]), t7 = pkw83(pksub(y[3], y[7]));
    v2f u0 = pkadd(t0, t2), u2 = pksub(t0, t2);
    v2f u1 = pkadd(t1, t3), w13 = pksub(t1, t3);           // u3 = i*w13 folded
    Y[0] = pkadd(u0, u1); Y[4] = pksub(u0, u1);
    Y[2] = pkaddi(u2, w13); Y[6] = pksubi(u2, w13);
    v2f v0 = pkaddi(t4, d26), v2 = pksubi(t4, d26);        // t4 +- i*d26
    v2f v1 = pkadd(t5, t7), w57 = pksub(t5, t7);           // v3 = i*w57 folded
    Y[1] = pkadd(v0, v1); Y[5] = pksub(v0, v1);
    Y[3] = pkaddi(v2, w57); Y[7] = pksubi(v2, w57);
}

// in-place variant (reads of y[] only in the t-layer; all writes after)
__device__ __forceinline__ void dft8p_ip(v2f y[8]) {
    v2f t0 = pkadd(y[0], y[4]), t4 = pksub(y[0], y[4]);
    v2f t1 = pkadd(y[1], y[5]), t5 = pkw8(pksub(y[1], y[5]));
    v2f t2 = pkadd(y[2], y[6]), d26 = pksub(y[2], y[6]);
    v2f t3 = pkadd(y[3], y[7]), t7 = pkw83(pksub(y[3], y[7]));
    v2f u0 = pkadd(t0, t2), u2 = pksub(t0, t2);
    v2f u1 = pkadd(t1, t3), w13 = pksub(t1, t3);
    y[0] = pkadd(u0, u1); y[4] = pksub(u0, u1);
    y[2] = pkaddi(u2, w13); y[6] = pksubi(u2, w13);
    v2f v0 = pkaddi(t4, d26), v2 = pksubi(t4, d26);
    v2f v1 = pkadd(t5, t7), w57 = pksub(t5, t7);
    y[1] = pkadd(v0, v1); y[5] = pksub(v0, v1);
    y[3] = pkaddi(v2, w57); y[7] = pksubi(v2, w57);
}

// final-layer DFT producing only outputs Y2,Y3,Y4,Y5 (the sensor v>>6 range)
__device__ __forceinline__ void dft8p_mid4(const v2f y[8], v2f o[4]) {
    v2f t0 = pkadd(y[0], y[4]), t4 = pksub(y[0], y[4]);
    v2f t1 = pkadd(y[1], y[5]), t5 = pkw8(pksub(y[1], y[5]));
    v2f t2 = pkadd(y[2], y[6]), d26 = pksub(y[2], y[6]);
    v2f t3 = pkadd(y[3], y[7]), t7 = pkw83(pksub(y[3], y[7]));
    v2f u0 = pkadd(t0, t2), u2 = pksub(t0, t2);
    v2f u1 = pkadd(t1, t3), w13 = pksub(t1, t3);
    v2f v0 = pkaddi(t4, d26), v2 = pksubi(t4, d26);
    v2f v1 = pkadd(t5, t7), w57 = pksub(t5, t7);
    o[0] = pkaddi(u2, w13);    // Y2
    o[1] = pkaddi(v2, w57);    // Y3
    o[2] = pksub(u0, u1);      // Y4
    o[3] = pksub(v0, v1);      // Y5
}

// W512^m from half-table
__device__ __forceinline__ v2f wlookup(const float2* trig, int m) {
    m &= 511;
    float2 ph = trig[m & 255];
    return (m & 256) ? v2f{-ph.x, -ph.y} : v2f{ph.x, ph.y};
}

// ---- in-register lane exchanges (transpose building blocks) -------------------------------------
template<int CTRL>
__device__ __forceinline__ float dppx(float x) {
    return __int_as_float(__builtin_amdgcn_mov_dpp(__float_as_int(x), CTRL, 0xF, 0xF, true));
}
__device__ __forceinline__ float swzx4(float x) {
    // BitMode swizzle: and=0x1F, or=0, xor=4  -> lane ^ 4
    return __int_as_float(__builtin_amdgcn_ds_swizzle(__float_as_int(x), 0x101F));
}

// xor1 exchange via fused v_cndmask_b32_dpp (dst = vcc ? src1 : dpp(src0)); constant lane
// masks in vcc via SALU. keepA = lanes where (L&1)==0, keepB = complement.
// Hazard: s_mov + s_nop 0 = 2 wait states before the first DPP (covers external VALU write).
__device__ __forceinline__ void xchg_x1(v2f& a, v2f& b,
                                        unsigned long long kA, unsigned long long kB) {
    v2f na, nb;
    asm("s_mov_b64 vcc, %[ka]\n\t"
        "s_nop 0\n\t"
        "v_cndmask_b32_dpp %[nax], %[bx], %[ax], vcc quad_perm:[1,0,3,2] row_mask:0xf bank_mask:0xf\n\t"
        "v_cndmask_b32_dpp %[nay], %[by], %[ay], vcc quad_perm:[1,0,3,2] row_mask:0xf bank_mask:0xf\n\t"
        "s_mov_b64 vcc, %[kb]\n\t"
        "s_nop 0\n\t"
        "v_cndmask_b32_dpp %[nbx], %[ax], %[bx], vcc quad_perm:[1,0,3,2] row_mask:0xf bank_mask:0xf\n\t"
        "v_cndmask_b32_dpp %[nby], %[ay], %[by], vcc quad_perm:[1,0,3,2] row_mask:0xf bank_mask:0xf"
        : [nax]"=&v"(na.x), [nay]"=&v"(na.y), [nbx]"=&v"(nb.x), [nby]"=&v"(nb.y)
        : [ax]"v"(a.x), [ay]"v"(a.y), [bx]"v"(b.x), [by]"v"(b.y),
          [ka]"s"(kA), [kb]"s"(kB)
        : "vcc");
    a = na; b = nb;
}
// xor2 exchange, quad_perm:[2,3,0,1]; keepA = lanes where (L&2)==0.
__device__ __forceinline__ void xchg_x2(v2f& a, v2f& b,
                                        unsigned long long kA, unsigned long long kB) {
    v2f na, nb;
    asm("s_mov_b64 vcc, %[ka]\n\t"
        "s_nop 0\n\t"
        "v_cndmask_b32_dpp %[nax], %[bx], %[ax], vcc quad_perm:[2,3,0,1] row_mask:0xf bank_mask:0xf\n\t"
        "v_cndmask_b32_dpp %[nay], %[by], %[ay], vcc quad_perm:[2,3,0,1] row_mask:0xf bank_mask:0xf\n\t"
        "s_mov_b64 vcc, %[kb]\n\t"
        "s_nop 0\n\t"
        "v_cndmask_b32_dpp %[nbx], %[ax], %[bx], vcc quad_perm:[2,3,0,1] row_mask:0xf bank_mask:0xf\n\t"
        "v_cndmask_b32_dpp %[nby], %[ay], %[by], vcc quad_perm:[2,3,0,1] row_mask:0xf bank_mask:0xf"
        : [nax]"=&v"(na.x), [nay]"=&v"(na.y), [nbx]"=&v"(nb.x), [nby]"=&v"(nb.y)
        : [ax]"v"(a.x), [ay]"v"(a.y), [bx]"v"(b.x), [by]"v"(b.y),
          [ka]"s"(kA), [kb]"s"(kB)
        : "vcc");
    a = na; b = nb;
}

#if __has_builtin(__builtin_amdgcn_update_dpp)
// xor4 exchange via masked-merge DPP (lane^4 stays within a 16-lane row).
// Convention (verified R27): row_ror:N -> dst lane i reads src (i-N)%16.
//   a' : banks 1,3 (L&4!=0) need b[L-4] -> row_ror:4  (0x124), bank_mask 0xA
//   b' : banks 0,2 (L&4==0) need a[L+4] -> row_ror:12 (0x12C), bank_mask 0x5
__device__ __forceinline__ void xchg4(v2f& a, v2f& b, bool /*bit*/) {
    int ax = __float_as_int(a.x), ay = __float_as_int(a.y);
    int bx = __float_as_int(b.x), by = __float_as_int(b.y);
    a.x = __int_as_float(__builtin_amdgcn_update_dpp(ax, bx, 0x124, 0xF, 0xA, false));
    a.y = __int_as_float(__builtin_amdgcn_update_dpp(ay, by, 0x124, 0xF, 0xA, false));
    b.x = __int_as_float(__builtin_amdgcn_update_dpp(bx, ax, 0x12C, 0xF, 0x5, false));
    b.y = __int_as_float(__builtin_amdgcn_update_dpp(by, ay, 0x12C, 0xF, 0x5, false));
}
// xor8 exchange via masked-merge DPP: row_ror:8 (self-inverse, direction-agnostic);
// bank_mask 0xC = lanes (L&8)!=0, 0x3 = rest. HW-validated since R21.
__device__ __forceinline__ void xchg8(v2f& a, v2f& b, bool /*bit*/) {
    int ax = __float_as_int(a.x), ay = __float_as_int(a.y);
    int bx = __float_as_int(b.x), by = __float_as_int(b.y);
    a.x = __int_as_float(__builtin_amdgcn_update_dpp(ax, bx, 0x128, 0xF, 0xC, false));
    a.y = __int_as_float(__builtin_amdgcn_update_dpp(ay, by, 0x128, 0xF, 0xC, false));
    b.x = __int_as_float(__builtin_amdgcn_update_dpp(bx, ax, 0x128, 0xF, 0x3, false));
    b.y = __int_as_float(__builtin_amdgcn_update_dpp(by, ay, 0x128, 0xF, 0x3, false));
}
#else
__device__ __forceinline__ void xchg4(v2f& a, v2f& b, bool bit) {
    float dbx = swzx4(b.x);
    float dby = swzx4(b.y);
    float dax = swzx4(a.x);
    float day = swzx4(a.y);
    a.x = bit ? dbx : a.x;   a.y = bit ? dby : a.y;
    b.x = bit ? b.x : dax;   b.y = bit ? b.y : day;
}
__device__ __forceinline__ void xchg8(v2f& a, v2f& b, bool bit) {
    float dbx = dppx<0x128>(b.x);
    float dby = dppx<0x128>(b.y);
    float dax = dppx<0x128>(a.x);
    float day = dppx<0x128>(a.y);
    a.x = bit ? dbx : a.x;   a.y = bit ? dby : a.y;
    b.x = bit ? b.x : dax;   b.y = bit ? b.y : day;
}
#endif

#if __has_builtin(__builtin_amdgcn_permlane16_swap)
__device__ __forceinline__ void pl16x(v2f& a, v2f& b) {
    v2u rx = __builtin_amdgcn_permlane16_swap(__float_as_uint(a.x), __float_as_uint(b.x), false, false);
    a.x = __uint_as_float(rx.x); b.x = __uint_as_float(rx.y);
    v2u ry = __builtin_amdgcn_permlane16_swap(__float_as_uint(a.y), __float_as_uint(b.y), false, false);
    a.y = __uint_as_float(ry.x); b.y = __uint_as_float(ry.y);
}
#else
__device__ __forceinline__ void pl16x(v2f& a, v2f& b) {
    bool bit = (threadIdx.x & 16) != 0;
    float sx = bit ? a.x : b.x, sy = bit ? a.y : b.y;
    float tx = __shfl_xor(sx, 16), ty = __shfl_xor(sy, 16);
    a.x = bit ? tx : a.x; a.y = bit ? ty : a.y;
    b.x = bit ? b.x : tx; b.y = bit ? b.y : ty;
}
#endif

#if __has_builtin(__builtin_amdgcn_permlane32_swap)
__device__ __forceinline__ void pl32x(v2f& a, v2f& b) {
    v2u rx = __builtin_amdgcn_permlane32_swap(__float_as_uint(a.x), __float_as_uint(b.x), false, false);
    a.x = __uint_as_float(rx.x); b.x = __uint_as_float(rx.y);
    v2u ry = __builtin_amdgcn_permlane32_swap(__float_as_uint(a.y), __float_as_uint(b.y), false, false);
    a.y = __uint_as_float(ry.x); b.y = __uint_as_float(ry.y);
}
#else
__device__ __forceinline__ void pl32x(v2f& a, v2f& b) {
    bool bit = (threadIdx.x & 32) != 0;
    float sx = bit ? a.x : b.x, sy = bit ? a.y : b.y;
    float tx = __shfl_xor(sx, 32), ty = __shfl_xor(sy, 32);
    a.x = bit ? tx : a.x; a.y = bit ? ty : a.y;
    b.x = bit ? b.x : tx; b.y = bit ? b.y : ty;
}
#endif

// hot-loop step: in-register 512-pt inverse DFT (8x8x8 four-step; transposes via
// permlane/DPP), publish G2..G5 to this step's parity buffer, ONE barrier, gather.
// awBase/ldsBase carry the parity offset (0 or 32) folded in by the caller.
__device__ __forceinline__ void fft_sample(
    const v2f y[8], const v2f tA[8], const v2f tB[8],
    bool b2, bool b3,
    char* awBase, const char* ldsBase, int spos, const v2f ph[RPB], bool active,
    float* pA)
{
    const unsigned long long K1A = 0x5555555555555555ULL;  // (L&1)==0
    const unsigned long long K1B = 0xAAAAAAAAAAAAAAAAULL;
    const unsigned long long K2A = 0x3333333333333333ULL;  // (L&2)==0
    const unsigned long long K2B = 0xCCCCCCCCCCCCCCCCULL;
    v2f G[8];
    dft8p(y, G);                                   // DFT over q2 (reg digit) -> v0
#pragma unroll
    for (int k1 = 1; k1 < 8; ++k1) G[k1] = cmulv(G[k1], tA[k1]);   // W512^{L*v0}
    // T1: reg digit (v0) <-> lane-high digit (q1)
    xchg8(G[0], G[1], b3);  xchg8(G[2], G[3], b3);                       // xor8 (merge-DPP)
    xchg8(G[4], G[5], b3);  xchg8(G[6], G[7], b3);
    pl16x(G[0], G[2]);  pl16x(G[1], G[3]);  pl16x(G[4], G[6]);  pl16x(G[5], G[7]);   // xor16
    pl32x(G[0], G[4]);  pl32x(G[1], G[5]);  pl32x(G[2], G[6]);  pl32x(G[3], G[7]);   // xor32
    dft8p_ip(G);                                   // DFT over q1 -> v1
#pragma unroll
    for (int m1 = 1; m1 < 8; ++m1) G[m1] = cmulv(G[m1], tB[m1]);   // W512^{8*q0*v1}
    // T2: reg digit (v1) <-> lane-low digit (q0)
    xchg_x1(G[0], G[1], K1A, K1B);  xchg_x1(G[2], G[3], K1A, K1B);       // cndmask_dpp xor1
    xchg_x1(G[4], G[5], K1A, K1B);  xchg_x1(G[6], G[7], K1A, K1B);
    xchg_x2(G[0], G[2], K2A, K2B);  xchg_x2(G[1], G[3], K2A, K2B);       // cndmask_dpp xor2
    xchg_x2(G[4], G[6], K2A, K2B);  xchg_x2(G[5], G[7], K2A, K2B);
    xchg4(G[0], G[4], b2);  xchg4(G[1], G[5], b2);                       // xor4 (merge-DPP)
    xchg4(G[2], G[6], b2);  xchg4(G[3], G[7], b2);
    v2f o[4];
    dft8p_mid4(G, o);                              // DFT over q0 -> v2 (only outputs 2..5)
    *(v4f*)(awBase +  0) = v4f{o[0].x, o[0].y, o[1].x, o[1].y};   // G2,G3
    *(v4f*)(awBase + 16) = v4f{o[2].x, o[2].y, o[3].x, o[3].y};   // G4,G5
    __syncthreads();   // single barrier: publish visible; orders prev gather vs buffer reuse
    if (active) {
        v2f accv = v2f{0.0f, 0.0f};
#pragma unroll
        for (int ww = 0; ww < RPB; ++ww) {
            v2f q = *(const v2f*)(ldsBase + ww * WREG + spos);
            // accv += {q.x*ph.x, -q.y*ph.y}
            asm("v_pk_fma_f32 %0, %1, %2, %0 neg_hi:[1,0,0]" : "+v"(accv) : "v"(q), "v"(ph[ww]));
        }
        pA[0] = accv.x + accv.y;
    }
}

// ---------------- init kernels (run once, shuffle FFT; cold path stays scalar) -------------------
__device__ __forceinline__ void cbfly(float& ar, float& ai, float& br, float& bi,
                                      float wr, float wi) {
    float dr = ar - br, di = ai - bi;
    ar = ar + br; ai = ai + bi;
    br = fmaf(dr, wr, -di * wi);
    bi = fmaf(dr, wi,  di * wr);
}

__device__ __forceinline__ void init_trig(float2* trig, int tid) {
    if (tid < 256) {
        float ang = (float)tid * (6.283185307179586f / 512.0f);
        float s, c;
        sincosf(ang, &s, &c);
        trig[tid] = make_float2(c, s);
    }
}

__device__ __forceinline__ void fft512_inv_lds(float* xr, float* xi, const float2* trig, int L) {
#pragma unroll
    for (int r = 0; r < 4; ++r) {
        float2 w = trig[(r << 6) + L];
        cbfly(xr[r], xi[r], xr[r + 4], xi[r + 4], w.x, w.y);
    }
    {
        float2 w0 = trig[L << 1];
        float2 w1 = trig[(64 + L) << 1];
        cbfly(xr[0], xi[0], xr[2], xi[2], w0.x, w0.y);
        cbfly(xr[1], xi[1], xr[3], xi[3], w1.x, w1.y);
        cbfly(xr[4], xi[4], xr[6], xi[6], w0.x, w0.y);
        cbfly(xr[5], xi[5], xr[7], xi[7], w1.x, w1.y);
    }
    {
        float2 w = trig[L << 2];
        cbfly(xr[0], xi[0], xr[1], xi[1], w.x, w.y);
        cbfly(xr[2], xi[2], xr[3], xi[3], w.x, w.y);
        cbfly(xr[4], xi[4], xr[5], xi[5], w.x, w.y);
        cbfly(xr[6], xi[6], xr[7], xi[7], w.x, w.y);
    }
#pragma unroll
    for (int s = 3; s <= 8; ++s) {
        const int half = 512 >> (s + 1);
        const int ex = (L & (half - 1)) << s;
        float2 w = trig[ex];
        const bool hi = (L & half) != 0;
        float wr = hi ? w.x : 1.0f;
        float wi = hi ? w.y : 0.0f;
        float sg = hi ? -1.0f : 1.0f;
#pragma unroll
        for (int r = 0; r < 8; ++r) {
            float orv = __shfl_xor(xr[r], half);
            float oiv = __shfl_xor(xi[r], half);
            float tr = fmaf(sg, xr[r], orv);
            float ti = fmaf(sg, xi[r], oiv);
            xr[r] = fmaf(tr, wr, -ti * wi);
            xi[r] = fmaf(tr, wi,  ti * wr);
        }
    }
}

__global__ __launch_bounds__(256) void f1_kernel(const float* __restrict__ f,
                                                 float2* __restrict__ R) {
    __shared__ float2 trig[256];
    const int tid = threadIdx.x;
    init_trig(trig, tid);
    __syncthreads();
    const int w = tid >> 6, L = tid & 63;
    const int x = 128 + blockIdx.x * 4 + w;   // nonzero rows only: [128, 384)
    const int b = blockIdx.y;
    const float* frow = f + ((size_t)b * 256 + (x - 128)) * 256;
    float xr[8], xi[8];
#pragma unroll
    for (int r = 0; r < 8; ++r) {
        int e = r * 64 + L;
        xr[r] = (e >= 128 && e < 384) ? frow[e - 128] : 0.0f;
        xi[r] = 0.0f;
    }
    fft512_inv_lds(xr, xi, trig, L);
    float2* Rrow = R + ((size_t)b * NOUT + x) * NOUT;
#pragma unroll
    for (int r = 0; r < 8; ++r) {
        int e = r * 64 + L;
        int k = __brev((unsigned)e) >> 23;
        Rrow[k] = make_float2(xr[r], -xi[r]);
    }
}

// f2: rows x outside [128,384) of R were never written (and are not zeroed) — treat as 0.
// e = r*64 + L is in [128,384) exactly for r in [2,6).
__global__ __launch_bounds__(256) void f2_kernel(const float2* __restrict__ R,
                                                 float2* __restrict__ A0) {
    __shared__ float2 trig[256];
    const int tid = threadIdx.x;
    init_trig(trig, tid);
    __syncthreads();
    const int w = tid >> 6, L = tid & 63;
    const int q = blockIdx.x * 4 + w;
    const int b = blockIdx.y;
    float xr[8], xi[8];
#pragma unroll
    for (int r = 0; r < 8; ++r) {
        if (r >= 2 && r < 6) {
            int e = r * 64 + L;
            float2 v = R[((size_t)b * NOUT + e) * NOUT + q];
            xr[r] = v.x;
            xi[r] = -v.y;
        } else {
            xr[r] = 0.0f;
            xi[r] = 0.0f;
        }
    }
    fft512_inv_lds(xr, xi, trig, L);
#pragma unroll
    for (int r = 0; r < 8; ++r) {
        int e = r * 64 + L;
        int p = __brev((unsigned)e) >> 23;
        A0[((size_t)b * NOUT + p) * NOUT + q] = make_float2(xr[r], -xi[r]);
    }
}

// ---------------- time-chunk simulation ----------------------------------------------------------
// block = (row group g of RPB rows, batch b); wave w owns row p = RPB*g + w, p in 0..257.
// Threads 0..255 each own one sensor, summing the block's RPB rows after the step barrier.
__global__ __launch_bounds__(384, 4) void sim_kernel(
    const float* __restrict__ fil,
    const int* __restrict__ idx0, const int* __restrict__ idx1,
    float2* __restrict__ stateCur, float2* __restrict__ statePrev,
    float* __restrict__ partial, int Tc, int firstChunk, int lastChunk)
{
    __shared__ __align__(16) char waveMem[RPB * WREG];   // 31104 B
    __shared__ float2 trig[256];                         //  2048 B -> 33152 B total

    const int tid = threadIdx.x;              // 0..383
    const int w = tid >> 6, L = tid & 63;
    const int g = blockIdx.x, b = blockIdx.y;
    const int p = g * RPB + w;                // 0..257

    if (tid < 256) {
        float ang = (float)tid * (6.283185307179586f / 512.0f);
        float s, c;
        sincosf(ang, &s, &c);
        trig[tid] = make_float2(c, s);
    }
    __syncthreads();

    // --- per-lane constant twiddles ---
    v2f tA[8], tB[8];
#pragma unroll
    for (int k1 = 1; k1 < 8; ++k1) tA[k1] = wlookup(trig, L * k1);
#pragma unroll
    for (int m1 = 1; m1 < 8; ++m1) tB[m1] = wlookup(trig, 8 * (L & 7) * m1);

    // --- transpose predicates (loop-invariant; used by fallback paths) ---
    const bool b2 = (L & 4) != 0;
    const bool b3 = (L & 8) != 0;

    // --- sensor constants: thread tid<256 owns sensor j=tid ---
    const bool active = tid < 256;
    int spos = 0;
    v2f ph[RPB];
    if (active) {
        int u = idx0[tid];
        int v = idx1[tid];
        // published regs are v>>6 in {2..5} at lane-local offsets 0,8,16,24 (parity 0)
        spos = ((v & 7) * 8 + ((v >> 3) & 7)) * 80 + ((v >> 6) * 8 - 16);
        // Hermitian fold phase: p==0 -> 1, p==256 -> (-1)^u, p==257 -> 0, else 2*W512^{pu}
#pragma unroll
        for (int ww = 0; ww < RPB; ++ww) {
            int prow = g * RPB + ww;
            v2f a0;
            if (prow == 0)        a0 = v2f{1.0f, 0.0f};
            else if (prow == 256) a0 = v2f{(u & 1) ? -1.0f : 1.0f, 0.0f};
            else if (prow == 257) a0 = v2f{0.0f, 0.0f};
            else                  a0 = 2.0f * wlookup(trig, prow * u);
            ph[ww] = a0;
        }
    } else {
#pragma unroll
        for (int ww = 0; ww < RPB; ++ww) ph[ww] = v2f{0.0f, 0.0f};
    }

    // --- per-lane LDS publish base; parity buffer offsets 0 / 32 within the pitch-80 slot ---
    char* myA    = waveMem + w * WREG;
    char* awBase = myA + L * 80;

    // --- load state + filter into registers ---
    v2f a[8], bb[8];
    float C[8];
    {
        const size_t rowBase = ((size_t)b * NOUT + p) * NOUT;
        const float* filRow = fil + (size_t)p * NOUT;
#pragma unroll
        for (int r = 0; r < 8; ++r) {
            int e = r * 64 + L;
            float2 a0 = stateCur[rowBase + e];
            a[r] = v2f{a0.x, a0.y};
            if (firstChunk) {
                bb[r] = a[r];
            } else {
                float2 a1 = statePrev[rowBase + e];
                bb[r] = v2f{a1.x, a1.y};
            }
            C[r] = fmaf(-4.0f, filRow[e], 2.0f);
        }
    }

    float* pOut = partial + ((size_t)g * Tc * NB + b) * NPHI + tid;

    for (int tl = 0; tl < Tc; tl += 2) {
        // step A (parity 0): bb becomes A_{t+1}
#pragma unroll
        for (int r = 0; r < 8; ++r) bb[r] = v2f{C[r], C[r]} * a[r] - bb[r];
        fft_sample(bb, tA, tB, b2, b3, awBase, waveMem,
                   spos, ph, active, pOut);
        pOut += NB * NPHI;
        // step B (parity 1): a becomes A_{t+2}
#pragma unroll
        for (int r = 0; r < 8; ++r) a[r] = v2f{C[r], C[r]} * bb[r] - a[r];
        fft_sample(a, tA, tB, b2, b3, awBase + 32, waveMem + 32,
                   spos, ph, active, pOut);
        pOut += NB * NPHI;
    }

    // --- save state for the next chunk (skipped when this is the last chunk) ---
    if (!lastChunk) {
        const size_t rowBase = ((size_t)b * NOUT + p) * NOUT;
#pragma unroll
        for (int r = 0; r < 8; ++r) {
            int e = r * 64 + L;
            stateCur[rowBase + e]  = make_float2(a[r].x, a[r].y);
            statePrev[rowBase + e] = make_float2(bb[r].x, bb[r].y);
        }
    }
}

// ---------------- reduce NGRP row-group partials -> out[b][j][t] ----------------------------------
__global__ __launch_bounds__(256) void reduce_kernel(const float* __restrict__ partial,
                                                     float* __restrict__ out,
                                                     int Tc, int tStart) {
    int id = blockIdx.x * 256 + threadIdx.x;   // over Tc*16*256, exact
    int j = id & 255;
    int b = (id >> 8) & 15;
    int tl = id >> 12;
    float s = 0.0f;
#pragma unroll
    for (int gg = 0; gg < NGRP; ++gg)
        s += partial[(((size_t)gg * Tc + tl) * NB + b) * NPHI + j];
    out[((size_t)b * NPHI + j) * NT + (tStart + tl)] = s * (1.0f / (512.0f * 512.0f));
}

extern "C" void kernel_launch(void* const* d_in, const int* in_sizes, int n_in,
                              void* d_out, int out_size, void* d_ws, size_t ws_size,
                              hipStream_t stream) {
    (void)in_sizes; (void)n_in; (void)out_size;
    const float* f   = (const float*)d_in[0];   // [16,1,256,256]
    const float* fil = (const float*)d_in[1];   // [512,512]
    const int* idx0  = (const int*)d_in[2];     // [256]
    const int* idx1  = (const int*)d_in[3];     // [256]
    float* out = (float*)d_out;                 // [16,1,256,240]

    char* ws = (char*)d_ws;
    const size_t stateBytes = (size_t)NB * NOUT * NOUT * sizeof(float2);  // 33.55 MB
    float2* stateCur  = (float2*)ws;
    float2* statePrev = (float2*)(ws + stateBytes);   // also reused as R scratch for f1/f2
    float*  partial   = (float*)(ws + 2 * stateBytes);
    size_t remain = (ws_size > 2 * stateBytes) ? ws_size - 2 * stateBytes : 0;

    // largest even time chunk whose partial buffer fits (even: the sim loop is 2-step unrolled)
    static const int tcs[] = {240, 120, 80, 60, 48, 40, 30, 24, 20, 16, 12, 10, 8, 6, 4, 2};
    int Tc = 2;
    for (int i = 0; i < 16; ++i) {
        size_t need = (size_t)NGRP * tcs[i] * NB * NPHI * sizeof(float);
        if (need <= remain) { Tc = tcs[i]; break; }
    }

    // no memset: f1 writes rows [128,384) of the R scratch; f2 skips the rest as known-zero
    f1_kernel<<<dim3(64, NB), 256, 0, stream>>>(f, statePrev);        // rows x in [128,384)
    f2_kernel<<<dim3(128, NB), 256, 0, stream>>>(statePrev, stateCur);
    for (int t0 = 0; t0 < NT; t0 += Tc) {
        int last = (t0 + Tc) >= NT ? 1 : 0;
        sim_kernel<<<dim3(NGRP, NB), RPB * 64, 0, stream>>>(fil, idx0, idx1, stateCur, statePrev,
                                                            partial, Tc, t0 == 0 ? 1 : 0, last);
        reduce_kernel<<<dim3(Tc * NB), 256, 0, stream>>>(partial, out, Tc, t0);
    }
}